// Round 1
// baseline (911.139 us; speedup 1.0000x reference)
//
#include <hip/hip_runtime.h>

#define NHEADS 8
#define DM 128
#define XS_LD 132    // x / attn_out row stride (floats): 16B-aligned rows, 2-way-free banks
#define QKV_LD 388   // qkv row stride (floats): 16B-aligned
#define WT_LD 132    // W tile row stride

// ---------- kernel 0: exclusive prefix sum of agents_per_sample ----------
__global__ void scan_offsets(const int* __restrict__ agents, int B, int* __restrict__ offs) {
    __shared__ int part[256];
    const int tid = threadIdx.x;
    const int per = (B + 255) >> 8;
    const int base = tid * per;
    int s = 0;
    for (int i = 0; i < per; ++i) {
        int idx = base + i;
        if (idx < B) s += agents[idx];
    }
    part[tid] = s;
    __syncthreads();
    for (int off = 1; off < 256; off <<= 1) {
        int v = (tid >= off) ? part[tid - off] : 0;
        __syncthreads();
        part[tid] += v;
        __syncthreads();
    }
    int run = (tid == 0) ? 0 : part[tid - 1];
    for (int i = 0; i < per; ++i) {
        int idx = base + i;
        if (idx < B) { offs[idx] = run; run += agents[idx]; }
    }
}

// ---------- kernel 1: fused MHSA, one block per sample ----------
__launch_bounds__(256)
__global__ void mhsa_fused(const float* __restrict__ x,
                           const float* __restrict__ wqkv,
                           const float* __restrict__ bqkv,
                           const float* __restrict__ wout,
                           const float* __restrict__ bout,
                           const int* __restrict__ agents,
                           const int* __restrict__ offs,
                           float* __restrict__ out) {
    __shared__ float xs[64 * XS_LD];     // x, later attn_out   (33.8 KB)
    __shared__ float qkv[64 * QKV_LD];   // q|k|v per token     (99.3 KB)
    __shared__ float wt[32 * WT_LD];     // staged weight tile  (16.9 KB)

    const int b = blockIdx.x;
    const int n = agents[b];
    const int base = offs[b];
    const int tid = threadIdx.x;
    const int nt = (n + 15) & ~15;       // token count rounded to wave-granular chunks

    // ---- Phase A: zero xs (incl. pads), then load x rows [n][128] ----
    for (int f = tid; f < 64 * (XS_LD / 4); f += 256)
        ((float4*)xs)[f] = make_float4(0.f, 0.f, 0.f, 0.f);
    __syncthreads();
    for (int f = tid; f < n * 32; f += 256) {
        int t = f >> 5, c = f & 31;
        float4 v = ((const float4*)(x + (size_t)(base + t) * DM))[c];
        *(float4*)&xs[t * XS_LD + (c << 2)] = v;
    }

    // thread tiling for GEMM phases: 2 tokens x 4 cols per thread
    const int jg = tid & 7;       // 8 col-lanes (cols j = jg + 8*jj, strided for bank-free wt reads)
    const int tg = tid >> 3;      // 32 token-groups of 2
    const int t0 = tg * 2;

    // ---- Phase B: qkv[n,384] = x @ Wqkv^T + b, 12 tiles of 32 cols ----
    for (int jt = 0; jt < 12; ++jt) {
        __syncthreads();
        for (int f = tid; f < 1024; f += 256) {
            int r = f >> 5, c = f & 31;
            float4 w = ((const float4*)(wqkv + (size_t)(jt * 32 + r) * DM))[c];
            *(float4*)&wt[r * WT_LD + (c << 2)] = w;
        }
        __syncthreads();
        if (t0 < nt) {
            float acc[2][4] = {};
            #pragma unroll 4
            for (int d = 0; d < DM; d += 4) {
                float4 x0 = *(const float4*)&xs[t0 * XS_LD + d];
                float4 x1 = *(const float4*)&xs[(t0 + 1) * XS_LD + d];
                #pragma unroll
                for (int jj = 0; jj < 4; ++jj) {
                    int j = jg + 8 * jj;
                    float4 w = *(const float4*)&wt[j * WT_LD + d];
                    acc[0][jj] += x0.x * w.x + x0.y * w.y + x0.z * w.z + x0.w * w.w;
                    acc[1][jj] += x1.x * w.x + x1.y * w.y + x1.z * w.z + x1.w * w.w;
                }
            }
            #pragma unroll
            for (int jj = 0; jj < 4; ++jj) {
                int col = jt * 32 + jg + 8 * jj;
                float bias = bqkv[col];
                qkv[t0 * QKV_LD + col] = acc[0][jj] + bias;
                qkv[(t0 + 1) * QKV_LD + col] = acc[1][jj] + bias;
            }
        }
    }
    __syncthreads();

    // ---- Phase C: per-head attention. 4 lanes per query row, 16 keys each (strided k=kk+4i) ----
    {
        const int tq = tid >> 2;
        const int kk = tid & 3;
        const float scale = 0.25f;  // 1/sqrt(16)
        if (tq < nt) {
            for (int h = 0; h < NHEADS; ++h) {
                const float* qrow = &qkv[tq * QKV_LD + h * 16];
                float4 q0 = *(const float4*)(qrow);
                float4 q1 = *(const float4*)(qrow + 4);
                float4 q2 = *(const float4*)(qrow + 8);
                float4 q3 = *(const float4*)(qrow + 12);
                float sc[16];
                float m = -3.0e38f;
                #pragma unroll
                for (int i = 0; i < 16; ++i) {
                    int k = kk + 4 * i;
                    float s = -3.0e38f;
                    if (k < n) {
                        const float* krow = &qkv[k * QKV_LD + DM + h * 16];
                        float4 k0 = *(const float4*)(krow);
                        float4 k1 = *(const float4*)(krow + 4);
                        float4 k2 = *(const float4*)(krow + 8);
                        float4 k3 = *(const float4*)(krow + 12);
                        s = (q0.x * k0.x + q0.y * k0.y + q0.z * k0.z + q0.w * k0.w +
                             q1.x * k1.x + q1.y * k1.y + q1.z * k1.z + q1.w * k1.w +
                             q2.x * k2.x + q2.y * k2.y + q2.z * k2.z + q2.w * k2.w +
                             q3.x * k3.x + q3.y * k3.y + q3.z * k3.z + q3.w * k3.w) * scale;
                    }
                    sc[i] = s;
                    m = fmaxf(m, s);
                }
                m = fmaxf(m, __shfl_xor(m, 1));
                m = fmaxf(m, __shfl_xor(m, 2));
                float l = 0.f;
                float acc[16] = {};
                #pragma unroll
                for (int i = 0; i < 16; ++i) {
                    int k = kk + 4 * i;
                    if (k < n) {
                        float p = __expf(sc[i] - m);
                        l += p;
                        const float* vrow = &qkv[k * QKV_LD + 2 * DM + h * 16];
                        #pragma unroll
                        for (int d = 0; d < 16; d += 4) {
                            float4 vv = *(const float4*)(vrow + d);
                            acc[d + 0] += p * vv.x;
                            acc[d + 1] += p * vv.y;
                            acc[d + 2] += p * vv.z;
                            acc[d + 3] += p * vv.w;
                        }
                    }
                }
                l += __shfl_xor(l, 1);
                l += __shfl_xor(l, 2);
                #pragma unroll
                for (int d = 0; d < 16; ++d) {
                    acc[d] += __shfl_xor(acc[d], 1);
                    acc[d] += __shfl_xor(acc[d], 2);
                }
                if (kk == 0) {
                    float inv = 1.0f / l;
                    #pragma unroll
                    for (int d = 0; d < 16; ++d)
                        xs[tq * XS_LD + h * 16 + d] = acc[d] * inv;
                }
            }
        }
    }
    __syncthreads();

    // ---- Phase D: out = attn_out @ Wout^T + b, 4 tiles of 32 cols, write global ----
    for (int et = 0; et < 4; ++et) {
        __syncthreads();
        for (int f = tid; f < 1024; f += 256) {
            int r = f >> 5, c = f & 31;
            float4 w = ((const float4*)(wout + (size_t)(et * 32 + r) * DM))[c];
            *(float4*)&wt[r * WT_LD + (c << 2)] = w;
        }
        __syncthreads();
        if (t0 < n) {
            float acc[2][4] = {};
            #pragma unroll 4
            for (int d = 0; d < DM; d += 4) {
                float4 x0 = *(const float4*)&xs[t0 * XS_LD + d];
                float4 x1 = *(const float4*)&xs[(t0 + 1) * XS_LD + d];
                #pragma unroll
                for (int jj = 0; jj < 4; ++jj) {
                    int j = jg + 8 * jj;
                    float4 w = *(const float4*)&wt[j * WT_LD + d];
                    acc[0][jj] += x0.x * w.x + x0.y * w.y + x0.z * w.z + x0.w * w.w;
                    acc[1][jj] += x1.x * w.x + x1.y * w.y + x1.z * w.z + x1.w * w.w;
                }
            }
            #pragma unroll
            for (int jj = 0; jj < 4; ++jj) {
                int col = et * 32 + jg + 8 * jj;
                float bias = bout[col];
                out[(size_t)(base + t0) * DM + col] = acc[0][jj] + bias;
                if (t0 + 1 < n)
                    out[(size_t)(base + t0 + 1) * DM + col] = acc[1][jj] + bias;
            }
        }
    }
}

extern "C" void kernel_launch(void* const* d_in, const int* in_sizes, int n_in,
                              void* d_out, int out_size, void* d_ws, size_t ws_size,
                              hipStream_t stream) {
    const float* att_in     = (const float*)d_in[0];
    const float* in_proj_w  = (const float*)d_in[1];
    const float* in_proj_b  = (const float*)d_in[2];
    const float* out_proj_w = (const float*)d_in[3];
    const float* out_proj_b = (const float*)d_in[4];
    const int*   agents     = (const int*)d_in[5];
    const int B = in_sizes[5];

    int* offs = (int*)d_ws;  // B ints of scratch
    hipLaunchKernelGGL(scan_offsets, dim3(1), dim3(256), 0, stream, agents, B, offs);
    hipLaunchKernelGGL(mhsa_fused, dim3(B), dim3(256), 0, stream,
                       att_in, in_proj_w, in_proj_b, out_proj_w, out_proj_b,
                       agents, offs, (float*)d_out);
}

// Round 3
// 390.271 us; speedup vs baseline: 2.3346x; 2.3346x over previous
//
#include <hip/hip_runtime.h>

#define DM 128
#define NHEADS 8

typedef __attribute__((ext_vector_type(8))) __bf16 bf16x8;
typedef __attribute__((ext_vector_type(4))) float f32x4;

__device__ inline unsigned short f2bf(float f) {
    unsigned u = __float_as_uint(f);
    u += 0x7FFFu + ((u >> 16) & 1u);
    return (unsigned short)(u >> 16);
}

// ---------------- LDS layout (bytes) ----------------
// K   [64][136] bf16  : 17408   (K tokens x dmodel-of-K)
// Vt  [128][72] bf16  : 18432   (V transposed: dim x token)
// XB  [64][136] bf16  : 17408   (x input, later attn_out)
// Q   [64][136] bf16  : 17408   (aliased by P [64][72] bf16 after preload)
// WT  [32][136] bf16  :  8704   (staged weight tile)
#define K_OFF   0
#define VT_OFF  17408
#define XB_OFF  35840
#define Q_OFF   53248
#define P_OFF   53248
#define WT_OFF  70656
#define SMEM_BYTES 79360

// ---------- prep: weight->bf16 conversion (blocks 0..63) + offset scan (block 64) ----------
__global__ void prep(const int* __restrict__ agents, int B,
                     const float* __restrict__ wqkv, const float* __restrict__ wout,
                     int* __restrict__ offs,
                     unsigned short* __restrict__ wqkv_bf,
                     unsigned short* __restrict__ wout_bf) {
    if (blockIdx.x < 64) {
        int idx = (blockIdx.x * 256 + threadIdx.x) * 4;   // 0..65532
        if (idx < 49152) {
            float4 v = *(const float4*)(wqkv + idx);
            ushort4 o;
            o.x = f2bf(v.x); o.y = f2bf(v.y); o.z = f2bf(v.z); o.w = f2bf(v.w);
            *(ushort4*)(wqkv_bf + idx) = o;
        } else {
            int j = idx - 49152;
            float4 v = *(const float4*)(wout + j);
            ushort4 o;
            o.x = f2bf(v.x); o.y = f2bf(v.y); o.z = f2bf(v.z); o.w = f2bf(v.w);
            *(ushort4*)(wout_bf + j) = o;
        }
    } else {
        __shared__ int part[256];
        const int tid = threadIdx.x;
        const int per = (B + 255) >> 8;
        const int base = tid * per;
        int s = 0;
        for (int i = 0; i < per; ++i) {
            int idx = base + i;
            if (idx < B) s += agents[idx];
        }
        part[tid] = s;
        __syncthreads();
        for (int off = 1; off < 256; off <<= 1) {
            int v = (tid >= off) ? part[tid - off] : 0;
            __syncthreads();
            part[tid] += v;
            __syncthreads();
        }
        int run = (tid == 0) ? 0 : part[tid - 1];
        for (int i = 0; i < per; ++i) {
            int idx = base + i;
            if (idx < B) { offs[idx] = run; run += agents[idx]; }
        }
    }
}

// ---------------- fused MHSA, one block per sample, 4 waves ----------------
__launch_bounds__(256, 2)
__global__ void mhsa(const float* __restrict__ x,
                     const unsigned short* __restrict__ wqkvb,
                     const float* __restrict__ bqkv,
                     const unsigned short* __restrict__ woutb,
                     const float* __restrict__ bout,
                     const int* __restrict__ agents,
                     const int* __restrict__ offs,
                     float* __restrict__ out) {
    __shared__ __align__(16) char smem[SMEM_BYTES];
    unsigned short* Kb = (unsigned short*)(smem + K_OFF);
    unsigned short* Vt = (unsigned short*)(smem + VT_OFF);
    unsigned short* XB = (unsigned short*)(smem + XB_OFF);
    unsigned short* Qb = (unsigned short*)(smem + Q_OFF);
    unsigned short* Pb = (unsigned short*)(smem + P_OFF);
    unsigned short* WT = (unsigned short*)(smem + WT_OFF);

    const int b = blockIdx.x;
    const int n = agents[b];
    const int base = offs[b];
    const int tid = threadIdx.x;
    const int wave = tid >> 6, lane = tid & 63;
    const int quad = lane >> 4, l16 = lane & 15;
    const int m0 = wave * 16;
    const bool active = (m0 < n);

    // ---- Phase A: zero K|Vt|XB span. CRITICAL: Vt token-columns beyond the
    // active-wave range are read by the PV MFMA (P=0 there, but 0*NaN=NaN if
    // LDS holds stale NaN bit patterns) -> must be zeroed, not left stale.
    for (int f = tid; f < 3328; f += 256)            // 53248 B = 3328 uint4
        ((uint4*)smem)[f] = make_uint4(0u, 0u, 0u, 0u);
    __syncthreads();
    for (int f = tid; f < n * 32; f += 256) {
        int t = f >> 5, c = f & 31;
        float4 v = ((const float4*)(x + (size_t)(base + t) * DM))[c];
        ushort4 o;
        o.x = f2bf(v.x); o.y = f2bf(v.y); o.z = f2bf(v.z); o.w = f2bf(v.w);
        *(ushort4*)(XB + t * 136 + c * 4) = o;
    }
    __syncthreads();

    // ---- Phase B: qkv = x @ Wqkv^T + b  (12 stages of 32 cols) ----
    for (int jt = 0; jt < 12; ++jt) {
        for (int f = tid; f < 512; f += 256) {       // 32 rows x 128 cols bf16
            int r = f >> 4, c = f & 15;
            uint4 w = *(const uint4*)(wqkvb + (jt * 32 + r) * 128 + c * 8);
            *(uint4*)(WT + r * 136 + c * 8) = w;
        }
        __syncthreads();
        if (active) {
            for (int nt2 = 0; nt2 < 2; ++nt2) {
                f32x4 acc = {0.f, 0.f, 0.f, 0.f};
                #pragma unroll
                for (int ks = 0; ks < 4; ++ks) {
                    bf16x8 a = *(const bf16x8*)(XB + (m0 + l16) * 136 + ks * 32 + quad * 8);
                    bf16x8 bb = *(const bf16x8*)(WT + (nt2 * 16 + l16) * 136 + ks * 32 + quad * 8);
                    acc = __builtin_amdgcn_mfma_f32_16x16x32_bf16(a, bb, acc, 0, 0, 0);
                }
                int col = jt * 32 + nt2 * 16 + l16;
                float bias = bqkv[col];
                #pragma unroll
                for (int r = 0; r < 4; ++r) {
                    int row = m0 + quad * 4 + r;
                    unsigned short v = f2bf(acc[r] + bias);
                    if (col < 128)       Qb[row * 136 + col] = v;
                    else if (col < 256)  Kb[row * 136 + (col - 128)] = v;
                    else                 Vt[(col - 256) * 72 + row] = v;
                }
            }
        }
        __syncthreads();
    }

    // ---- Q preload into registers (A-layout, head_dim 16 zero-padded to K=32) ----
    bf16x8 qf[NHEADS];
    #pragma unroll
    for (int h = 0; h < NHEADS; ++h) qf[h] = (bf16x8)(__bf16)0.0f;
    if (active) {
        #pragma unroll
        for (int h = 0; h < NHEADS; ++h) {
            if (quad < 2)
                qf[h] = *(const bf16x8*)(Qb + (m0 + l16) * 136 + h * 16 + quad * 8);
        }
    }
    __syncthreads();   // P buffer aliases Q: all waves must finish Q reads first

    // ---- Phase C: attention, per head; no barriers (P/attn_out rows are wave-private) ----
    if (active) {
        for (int h = 0; h < NHEADS; ++h) {
            f32x4 sc[4];
            #pragma unroll
            for (int kt = 0; kt < 4; ++kt) {
                bf16x8 bb = *(const bf16x8*)(Kb + (kt * 16 + l16) * 136 + h * 16 + quad * 8);
                sc[kt] = __builtin_amdgcn_mfma_f32_16x16x32_bf16(qf[h], bb,
                          (f32x4){0.f, 0.f, 0.f, 0.f}, 0, 0, 0);
            }
            float p[4][4];
            #pragma unroll
            for (int r = 0; r < 4; ++r) {
                float mm = -1e30f;
                #pragma unroll
                for (int kt = 0; kt < 4; ++kt) {
                    int key = kt * 16 + l16;
                    float v = (key < n) ? sc[kt][r] * 0.25f : -1e30f;   // scale = 1/sqrt(16)
                    p[r][kt] = v;
                    mm = fmaxf(mm, v);
                }
                mm = fmaxf(mm, __shfl_xor(mm, 1));
                mm = fmaxf(mm, __shfl_xor(mm, 2));
                mm = fmaxf(mm, __shfl_xor(mm, 4));
                mm = fmaxf(mm, __shfl_xor(mm, 8));
                float ll = 0.f;
                #pragma unroll
                for (int kt = 0; kt < 4; ++kt) {
                    float e = __expf(p[r][kt] - mm);
                    p[r][kt] = e;
                    ll += e;
                }
                ll += __shfl_xor(ll, 1);
                ll += __shfl_xor(ll, 2);
                ll += __shfl_xor(ll, 4);
                ll += __shfl_xor(ll, 8);
                float inv = 1.0f / ll;
                #pragma unroll
                for (int kt = 0; kt < 4; ++kt)
                    Pb[(m0 + quad * 4 + r) * 72 + kt * 16 + l16] = f2bf(p[r][kt] * inv);
            }
            // PV: out[q][d] = P[q,keys] @ V[keys,d]
            f32x4 o = {0.f, 0.f, 0.f, 0.f};
            #pragma unroll
            for (int ks = 0; ks < 2; ++ks) {
                bf16x8 a = *(const bf16x8*)(Pb + (m0 + l16) * 72 + ks * 32 + quad * 8);
                bf16x8 bb = *(const bf16x8*)(Vt + (h * 16 + l16) * 72 + ks * 32 + quad * 8);
                o = __builtin_amdgcn_mfma_f32_16x16x32_bf16(a, bb, o, 0, 0, 0);
            }
            #pragma unroll
            for (int r = 0; r < 4; ++r)
                XB[(m0 + quad * 4 + r) * 136 + h * 16 + l16] = f2bf(o[r]);
        }
    }
    __syncthreads();

    // ---- Phase D: out = attn_out @ Wout^T + b  (4 stages of 32 cols), write global ----
    for (int et2 = 0; et2 < 4; ++et2) {
        for (int f = tid; f < 512; f += 256) {
            int r = f >> 4, c = f & 15;
            uint4 w = *(const uint4*)(woutb + (et2 * 32 + r) * 128 + c * 8);
            *(uint4*)(WT + r * 136 + c * 8) = w;
        }
        __syncthreads();
        if (active) {
            for (int nt2 = 0; nt2 < 2; ++nt2) {
                f32x4 acc = {0.f, 0.f, 0.f, 0.f};
                #pragma unroll
                for (int ks = 0; ks < 4; ++ks) {
                    bf16x8 a = *(const bf16x8*)(XB + (m0 + l16) * 136 + ks * 32 + quad * 8);
                    bf16x8 bb = *(const bf16x8*)(WT + (nt2 * 16 + l16) * 136 + ks * 32 + quad * 8);
                    acc = __builtin_amdgcn_mfma_f32_16x16x32_bf16(a, bb, acc, 0, 0, 0);
                }
                int col = et2 * 32 + nt2 * 16 + l16;
                float bias = bout[col];
                #pragma unroll
                for (int r = 0; r < 4; ++r) {
                    int row = m0 + quad * 4 + r;
                    if (row < n)
                        out[(size_t)(base + row) * DM + col] = acc[r] + bias;
                }
            }
        }
        __syncthreads();
    }
}

extern "C" void kernel_launch(void* const* d_in, const int* in_sizes, int n_in,
                              void* d_out, int out_size, void* d_ws, size_t ws_size,
                              hipStream_t stream) {
    const float* att_in     = (const float*)d_in[0];
    const float* in_proj_w  = (const float*)d_in[1];
    const float* in_proj_b  = (const float*)d_in[2];
    const float* out_proj_w = (const float*)d_in[3];
    const float* out_proj_b = (const float*)d_in[4];
    const int*   agents     = (const int*)d_in[5];
    const int B = in_sizes[5];

    // ws layout: offs [B*4 B] | wqkv_bf16 [98304 B] | wout_bf16 [32768 B]
    int* offs = (int*)d_ws;
    unsigned short* wqkv_bf = (unsigned short*)((char*)d_ws + 8192);
    unsigned short* wout_bf = (unsigned short*)((char*)d_ws + 8192 + 98304);

    hipLaunchKernelGGL(prep, dim3(65), dim3(256), 0, stream,
                       agents, B, in_proj_w, out_proj_w, offs, wqkv_bf, wout_bf);
    hipLaunchKernelGGL(mhsa, dim3(B), dim3(256), 0, stream,
                       att_in, wqkv_bf, in_proj_b, wout_bf, out_proj_b,
                       agents, offs, (float*)d_out);
}